// Round 8
// baseline (241.557 us; speedup 1.0000x reference)
//
#include <hip/hip_runtime.h>
#include <math.h>

#define NUM_C 16
#define DIMS 512
#define CHUNKS 128  // row-chunks per class -> 16*128 = 2048 segsum blocks (8/CU)

__device__ inline void atomAddF(float* p, float v) { unsafeAtomicAdd(p, v); }

// ws layout (contiguous zero region first):
//   gcur  @ 0      : 16 ints   (atomic append cursors; final value == counts)
//   gsum  @ 256    : 16*512 f32 (32 KB)
//   gsq   @ 33024  : 16*512 f32 (32 KB)
//   perm  @ 65792  : 16 * N ints (fixed per-class capacity N; ~4 MB)

// ---------------- K1: single-pass scatter (counts+prefix+scatter fused) -----
__global__ __launch_bounds__(256) void k_scatter1p(const int* __restrict__ bids,
                                                   int* __restrict__ gcur,
                                                   int* __restrict__ perm,
                                                   float* __restrict__ out, int n) {
    __shared__ int lh[NUM_C], lb[NUM_C], lc[NUM_C];
    const int tid = threadIdx.x;
    if (blockIdx.x == 0 && tid == 0) out[0] = 0.f;
    if (tid < NUM_C) lh[tid] = 0;
    __syncthreads();
    const int i0 = (blockIdx.x * 256 + tid) * 4;
    int4 c4 = make_int4(0, 0, 0, 0);
    const bool ok = (i0 + 3 < n);
    if (ok) {
        c4 = *reinterpret_cast<const int4*>(bids + i0);
        atomicAdd(&lh[c4.x], 1); atomicAdd(&lh[c4.y], 1);
        atomicAdd(&lh[c4.z], 1); atomicAdd(&lh[c4.w], 1);
    }
    __syncthreads();
    if (tid < NUM_C) {
        lb[tid] = tid * n + atomicAdd(&gcur[tid], lh[tid]);  // region base + cursor
        lc[tid] = 0;
    }
    __syncthreads();
    if (ok) {
        perm[lb[c4.x] + atomicAdd(&lc[c4.x], 1)] = i0;
        perm[lb[c4.y] + atomicAdd(&lc[c4.y], 1)] = i0 + 1;
        perm[lb[c4.z] + atomicAdd(&lc[c4.z], 1)] = i0 + 2;
        perm[lb[c4.w] + atomicAdd(&lc[c4.w], 1)] = i0 + 3;
    }
}

// ---------------- K2: per-class sum / sumsq, register accumulators ----------
// Block = (class c, chunk); class uniform -> acc in float4 regs (8 VGPRs).
// 256 threads = two 128-thread halves, each owning a CONTIGUOUS sub-range of
// the chunk's rows: per iteration one aligned int4 perm load (4 row indices)
// prefetched one window ahead, then 4 independent 1KB row loads (float4/lane).
// 2048 blocks = 8/CU = 32 waves/CU for latency hiding.
__global__ __launch_bounds__(256) void k_segsum(const float* __restrict__ hidden,
                                                const int* __restrict__ perm,
                                                const int* __restrict__ gcur,
                                                float* __restrict__ gsum,
                                                float* __restrict__ gsq, int n) {
    const int tid = threadIdx.x;
    const int c = blockIdx.x & (NUM_C - 1);
    const int chunk = blockIdx.x >> 4;
    const int cnt = gcur[c];
    const int base = c * n;
    const int len = (cnt + CHUNKS - 1) / CHUNKS;
    const int lo = min(chunk * len, cnt);
    const int hi = min(lo + len, cnt);
    const int half = tid >> 7, ht = tid & 127;
    const int span = hi - lo;
    const int mid = lo + (span >> 1);
    int k  = (half == 0) ? lo : mid;
    const int ke = (half == 0) ? mid : hi;

    float4 s = {0.f, 0.f, 0.f, 0.f}, q = {0.f, 0.f, 0.f, 0.f};
#define LOADROW(r) (*(reinterpret_cast<const float4*>(hidden + (size_t)(r) * DIMS) + ht))
#define ACC(v) { s.x += (v).x; s.y += (v).y; s.z += (v).z; s.w += (v).w; \
                 q.x += (v).x*(v).x; q.y += (v).y*(v).y; q.z += (v).z*(v).z; q.w += (v).w*(v).w; }

    // align to 4-int boundary for int4 perm loads
    while (k < ke && ((base + k) & 3)) {
        const float4 v = LOADROW(perm[base + k]);
        ACC(v);
        ++k;
    }
    if (k + 3 < ke) {
        int4 r = *reinterpret_cast<const int4*>(&perm[base + k]);
        for (; k + 7 < ke; k += 4) {
            const int4 rn = *reinterpret_cast<const int4*>(&perm[base + k + 4]);  // prefetch
            const float4 v0 = LOADROW(r.x), v1 = LOADROW(r.y);
            const float4 v2 = LOADROW(r.z), v3 = LOADROW(r.w);
            ACC(v0); ACC(v1); ACC(v2); ACC(v3);
            r = rn;
        }
        const float4 v0 = LOADROW(r.x), v1 = LOADROW(r.y);
        const float4 v2 = LOADROW(r.z), v3 = LOADROW(r.w);
        ACC(v0); ACC(v1); ACC(v2); ACC(v3);
        k += 4;
    }
    for (; k < ke; ++k) {
        const float4 v = LOADROW(perm[base + k]);
        ACC(v);
    }
#undef LOADROW
#undef ACC

    // combine the two halves through LDS, then native-f32 atomic flush
    __shared__ float red[128 * 8];
    if (half == 1) {
        float* p = &red[ht * 8];
        p[0] = s.x; p[1] = s.y; p[2] = s.z; p[3] = s.w;
        p[4] = q.x; p[5] = q.y; p[6] = q.z; p[7] = q.w;
    }
    __syncthreads();
    if (half == 0) {
        const float* p = &red[ht * 8];
        s.x += p[0]; s.y += p[1]; s.z += p[2]; s.w += p[3];
        q.x += p[4]; q.y += p[5]; q.z += p[6]; q.w += p[7];
        float* gs = gsum + c * DIMS + 4 * ht;
        float* gq = gsq  + c * DIMS + 4 * ht;
        atomAddF(gs + 0, s.x); atomAddF(gs + 1, s.y);
        atomAddF(gs + 2, s.z); atomAddF(gs + 3, s.w);
        atomAddF(gq + 0, q.x); atomAddF(gq + 1, q.y);
        atomAddF(gq + 2, q.z); atomAddF(gq + 3, q.w);
    }
}

// ---------------- K3: pairs — inline means/withins, sort, Simpson betainc ---
// I_x(1/2,b) = (2/B(1/2,b)) * Int_0^sqrt(x) (1-u^2)^(b-1) du
// Composite Simpson (256 intervals), f32, 8 lanes per x-value.
// Monotone in x -> top-d of betainc == betainc of top-d x (sort x only).
__global__ __launch_bounds__(512) void k_pairs(const float* __restrict__ gsum,
                                               const float* __restrict__ gsq,
                                               const int* __restrict__ gcur,
                                               const int* __restrict__ dptr,
                                               float* __restrict__ out) {
    __shared__ float xs[DIMS];
    __shared__ float wsum[8];
    const int tid = threadIdx.x;

    int p = blockIdx.x, i = 0, rem = p;
    while (rem >= NUM_C - 1 - i) { rem -= NUM_C - 1 - i; ++i; }
    const int j = i + 1 + rem;

    const float ni = (float)gcur[i], nj = (float)gcur[j];
    const float pc = ni + nj;

    {
        const float si = gsum[i * DIMS + tid];
        const float sj = gsum[j * DIMS + tid];
        const float mi = si / ni, mj = sj / nj;
        float wi = gsq[i * DIMS + tid] - si * mi;  wi = wi > 0.f ? wi : 0.f;
        float wj = gsq[j * DIMS + tid] - sj * mj;  wj = wj > 0.f ? wj : 0.f;
        const float hd = (mi - mj) * 0.5f;
        const float between = hd * hd * pc;
        const float within = wi + wj;
        float x = between / (between + within);
        if (!(x >= 1e-37f)) x = 1e-37f;          // also catches NaN
        const float XM = 1.0f - 1e-5f;
        if (x > XM) x = XM;
        xs[tid] = x;
    }

    // bitonic sort descending (f32)
    for (int kk = 2; kk <= DIMS; kk <<= 1) {
        for (int jj = kk >> 1; jj > 0; jj >>= 1) {
            __syncthreads();
            const int ixj = tid ^ jj;
            if (ixj > tid) {
                const float va = xs[tid], vb = xs[ixj];
                const bool sw = ((tid & kk) == 0) ? (va < vb) : (va > vb);
                if (sw) { xs[tid] = vb; xs[ixj] = va; }
            }
        }
    }
    __syncthreads();

    const int d = *dptr;
    float d2 = pc - 2.0f;
    if (d2 == 0.0f) d2 = 1e-5f;
    const float b = d2 * 0.5f;
    const float bm1 = b - 1.0f;
    const float invb = 1.0f / b;
    // ln(2/B) = ln2 - [0.5*(ln pi - ln b) + log1p(1/(8b) + 1/(128 b^2))]
    const float ln2overB = 0.69314718f
        - (0.5f * (1.14472989f - logf(b)) + log1pf(invb * (0.125f + 0.0078125f * invb)));

    const int sub = tid & 7;
    const int rounds = (d + 63) >> 6;            // q-groups of 64 per pass
    float part = 0.f;
    for (int r = 0; r < rounds; ++r) {
        const int q = (tid >> 3) + (r << 6);
        const bool act = (q < d);
        const float x = xs[act ? q : 0];
        const float rt = sqrtf(x);
        const float h = rt * (1.0f / 256.0f);
        float acc = 0.f;
        for (int k = sub; k <= 256; k += 8) {
            const float sv = (float)k * h;
            const float w = (k == 0 || k == 256) ? 1.f : ((k & 1) ? 4.f : 2.f);
            acc += w * __expf(bm1 * log1pf(-sv * sv));
        }
        acc += __shfl_down(acc, 4, 64);
        acc += __shfl_down(acc, 2, 64);
        acc += __shfl_down(acc, 1, 64);
        if (sub == 0 && act) {
            float li = logf(acc * h * (1.0f / 3.0f)) + ln2overB;
            part += (li < 0.f) ? li : 0.f;       // betainc <= 1
        }
    }
    for (int off = 32; off > 0; off >>= 1) part += __shfl_down(part, off, 64);
    if ((tid & 63) == 0) wsum[tid >> 6] = part;
    __syncthreads();
    if (tid == 0) {
        float t = 0.f;
        for (int w = 0; w < 8; ++w) t += wsum[w];
        atomAddF(out, -t);
    }
}

// ---------------- launch: 4 graph nodes total ----------------
extern "C" void kernel_launch(void* const* d_in, const int* in_sizes, int n_in,
                              void* d_out, int out_size, void* d_ws, size_t ws_size,
                              hipStream_t stream) {
    const float* hidden = (const float*)d_in[0];
    const int* bids = (const int*)d_in[1];
    const int* dptr = (const int*)d_in[2];
    float* out = (float*)d_out;
    const int N = in_sizes[1];

    char* ws = (char*)d_ws;
    int*   gcur = (int*)(ws + 0);        // 16 ints (cursor == counts when done)
    float* gsum = (float*)(ws + 256);    // 16*512 f32
    float* gsq  = (float*)(ws + 33024);  // 16*512 f32
    int*   perm = (int*)(ws + 65792);    // 16 * N ints (per-class capacity N)

    hipMemsetAsync(d_ws, 0, 65792, stream);                 // gcur + gsum + gsq

    const int nb = (N + 1023) / 1024;                       // 4 ids/thread
    k_scatter1p<<<nb, 256, 0, stream>>>(bids, gcur, perm, out, N);
    k_segsum  <<<NUM_C * CHUNKS, 256, 0, stream>>>(hidden, perm, gcur, gsum, gsq, N);
    k_pairs   <<<NUM_C * (NUM_C - 1) / 2, 512, 0, stream>>>(gsum, gsq, gcur, dptr, out);
}

// Round 9
// 227.649 us; speedup vs baseline: 1.0611x; 1.0611x over previous
//
#include <hip/hip_runtime.h>
#include <math.h>

#define NUM_C 16
#define DIMS 512
#define RPC 128              // rows per chunk in k_stream
#define NCHUNK 512           // 65536 / RPC
#define GRP 16               // reducer groups per (class, half) in k_reduce
#define CPG (NCHUNK / GRP)   // chunks per reducer group = 32

__device__ inline void atomAddF(float* p, float v) { unsafeAtomicAdd(p, v); }

// ws layout:
//   psum  @ 0        : 1024 blk * 16 c * 256 d * f32 = 16 MB
//   psq   @ 16 MB    : 16 MB
//   pcnt  @ 32 MB    : 512 chunks * 16 ints = 32 KB
//   p2sum @ 32M+32K  : 16 c * 2 g * 16 grp * 256 d * f32 = 512 KB
//   p2sq  @ +512 KB  : 512 KB
//   cnt2  @ +512 KB  : 16 c * 16 grp ints = 1 KB
// Everything fully written before read -> NO memset nodes needed.

// ---------------- K1: streaming per-chunk per-class sum/sumsq ----------------
// Block = (g = dim-half, chunk of 128 rows). hidden read SEQUENTIALLY.
// Thread t exclusively owns LDS column (c, t) for all c -> plain RMW, no
// atomics, no __syncthreads anywhere. 8-row double-buffered prefetch.
// SoA f32 LDS (stride 4B): 64 lanes over 32 banks = 2/bank = conflict-free.
// Flush: coalesced global stores of per-block partials (no atomics).
__global__ __launch_bounds__(256) void k_stream(const float* __restrict__ hidden,
                                                const int* __restrict__ bids,
                                                float* __restrict__ psum,
                                                float* __restrict__ psq,
                                                int* __restrict__ pcnt) {
    __shared__ float lsum[NUM_C * 256];
    __shared__ float lsq[NUM_C * 256];
    const int tid = threadIdx.x;
    const int g = blockIdx.x & 1;
    const int chunk = blockIdx.x >> 1;

    #pragma unroll
    for (int c = 0; c < NUM_C; ++c) { lsum[c * 256 + tid] = 0.f; lsq[c * 256 + tid] = 0.f; }

    const int rowbase = chunk * RPC;
    const float* hp = hidden + (size_t)rowbase * DIMS + g * 256 + tid;
    const int* bp = bids + rowbase;

    int mycnt = 0;   // lanes 0..15: rows in this chunk with class == tid

    float va[8]; int ca[8];
    #pragma unroll
    for (int u = 0; u < 8; ++u) { va[u] = hp[(size_t)u * DIMS]; ca[u] = bp[u]; }

    for (int it = 0; it < RPC / 8 - 1; ++it) {
        float vb[8]; int cb[8];
        const float* hp2 = hp + (size_t)(it + 1) * 8 * DIMS;
        const int* bp2 = bp + (it + 1) * 8;
        #pragma unroll
        for (int u = 0; u < 8; ++u) { vb[u] = hp2[(size_t)u * DIMS]; cb[u] = bp2[u]; }
        #pragma unroll
        for (int u = 0; u < 8; ++u) {
            const int idx = ca[u] * 256 + tid;
            lsum[idx] += va[u];
            lsq[idx]  += va[u] * va[u];
            mycnt += (ca[u] == tid) ? 1 : 0;
        }
        #pragma unroll
        for (int u = 0; u < 8; ++u) { va[u] = vb[u]; ca[u] = cb[u]; }
    }
    #pragma unroll
    for (int u = 0; u < 8; ++u) {
        const int idx = ca[u] * 256 + tid;
        lsum[idx] += va[u];
        lsq[idx]  += va[u] * va[u];
        mycnt += (ca[u] == tid) ? 1 : 0;
    }

    // flush own column -> coalesced partial stores (1 KB per class row)
    float* ps = psum + (size_t)blockIdx.x * NUM_C * 256 + tid;
    float* pq = psq  + (size_t)blockIdx.x * NUM_C * 256 + tid;
    #pragma unroll
    for (int c = 0; c < NUM_C; ++c) {
        ps[c * 256] = lsum[c * 256 + tid];
        pq[c * 256] = lsq[c * 256 + tid];
    }
    if (g == 0 && tid < NUM_C) pcnt[chunk * NUM_C + tid] = mycnt;
}

// ---------------- K2: tree-reduce partials (no atomics) ----------------
// 512 blocks = (c, g, grp); each sums 32 chunks' 1 KB segments (coalesced),
// writes one 1 KB segment of p2. g==0/tid==0 also reduces counts. Block 0
// zeroes out (stream-ordered before k_pairs).
__global__ __launch_bounds__(256) void k_reduce(const float* __restrict__ psum,
                                                const float* __restrict__ psq,
                                                const int* __restrict__ pcnt,
                                                float* __restrict__ p2sum,
                                                float* __restrict__ p2sq,
                                                int* __restrict__ cnt2,
                                                float* __restrict__ out) {
    const int tid = threadIdx.x;
    const int bid = blockIdx.x;
    const int c = bid >> 5;
    const int g = (bid >> 4) & 1;
    const int grp = bid & 15;
    if (bid == 0 && tid == 0) out[0] = 0.f;

    float s = 0.f, q = 0.f;
    #pragma unroll 4
    for (int k = 0; k < CPG; ++k) {
        const int chunk = grp * CPG + k;
        const size_t seg = ((size_t)(chunk * 2 + g) * NUM_C + c) * 256 + tid;
        s += psum[seg];
        q += psq[seg];
    }
    p2sum[((c * 2 + g) * GRP + grp) * 256 + tid] = s;
    p2sq [((c * 2 + g) * GRP + grp) * 256 + tid] = q;

    if (g == 0 && tid == 0) {
        int cc = 0;
        for (int k = 0; k < CPG; ++k) cc += pcnt[(grp * CPG + k) * NUM_C + c];
        cnt2[c * GRP + grp] = cc;
    }
}

// ---------------- K3: pairs — reduce p2 inline, sort, Simpson betainc -------
// I_x(1/2,b) = (2/B(1/2,b)) * Int_0^sqrt(x) (1-u^2)^(b-1) du
// Composite Simpson (256 intervals), f32, 8 lanes per x-value.
// Monotone in x -> top-d of betainc == betainc of top-d x (sort x only).
__global__ __launch_bounds__(512) void k_pairs(const float* __restrict__ p2sum,
                                               const float* __restrict__ p2sq,
                                               const int* __restrict__ cnt2,
                                               const int* __restrict__ dptr,
                                               float* __restrict__ out) {
    __shared__ float xs[DIMS];
    __shared__ float wsum[8];
    const int tid = threadIdx.x;

    int p = blockIdx.x, i = 0, rem = p;
    while (rem >= NUM_C - 1 - i) { rem -= NUM_C - 1 - i; ++i; }
    const int j = i + 1 + rem;

    int cnti = 0, cntj = 0;
    #pragma unroll
    for (int gq = 0; gq < GRP; ++gq) { cnti += cnt2[i * GRP + gq]; cntj += cnt2[j * GRP + gq]; }
    const float ni = (float)cnti, nj = (float)cntj;
    const float pc = ni + nj;

    {
        const int g = tid >> 8, dl = tid & 255;
        float si = 0.f, qi = 0.f, sj = 0.f, qj = 0.f;
        #pragma unroll
        for (int gq = 0; gq < GRP; ++gq) {
            si += p2sum[((i * 2 + g) * GRP + gq) * 256 + dl];
            qi += p2sq [((i * 2 + g) * GRP + gq) * 256 + dl];
            sj += p2sum[((j * 2 + g) * GRP + gq) * 256 + dl];
            qj += p2sq [((j * 2 + g) * GRP + gq) * 256 + dl];
        }
        const float mi = si / ni, mj = sj / nj;
        float wi = qi - si * mi;  wi = wi > 0.f ? wi : 0.f;
        float wj = qj - sj * mj;  wj = wj > 0.f ? wj : 0.f;
        const float hd = (mi - mj) * 0.5f;
        const float between = hd * hd * pc;
        const float within = wi + wj;
        float x = between / (between + within);
        if (!(x >= 1e-37f)) x = 1e-37f;          // also catches NaN
        const float XM = 1.0f - 1e-5f;
        if (x > XM) x = XM;
        xs[tid] = x;
    }

    // bitonic sort descending (f32)
    for (int kk = 2; kk <= DIMS; kk <<= 1) {
        for (int jj = kk >> 1; jj > 0; jj >>= 1) {
            __syncthreads();
            const int ixj = tid ^ jj;
            if (ixj > tid) {
                const float va = xs[tid], vb = xs[ixj];
                const bool sw = ((tid & kk) == 0) ? (va < vb) : (va > vb);
                if (sw) { xs[tid] = vb; xs[ixj] = va; }
            }
        }
    }
    __syncthreads();

    const int d = *dptr;
    float d2 = pc - 2.0f;
    if (d2 == 0.0f) d2 = 1e-5f;
    const float b = d2 * 0.5f;
    const float bm1 = b - 1.0f;
    const float invb = 1.0f / b;
    // ln(2/B) = ln2 - [0.5*(ln pi - ln b) + log1p(1/(8b) + 1/(128 b^2))]
    const float ln2overB = 0.69314718f
        - (0.5f * (1.14472989f - logf(b)) + log1pf(invb * (0.125f + 0.0078125f * invb)));

    const int sub = tid & 7;
    const int rounds = (d + 63) >> 6;            // q-groups of 64 per pass
    float part = 0.f;
    for (int r = 0; r < rounds; ++r) {
        const int q = (tid >> 3) + (r << 6);
        const bool act = (q < d);
        const float x = xs[act ? q : 0];
        const float rt = sqrtf(x);
        const float h = rt * (1.0f / 256.0f);
        float acc = 0.f;
        for (int k = sub; k <= 256; k += 8) {
            const float sv = (float)k * h;
            const float w = (k == 0 || k == 256) ? 1.f : ((k & 1) ? 4.f : 2.f);
            acc += w * __expf(bm1 * log1pf(-sv * sv));
        }
        acc += __shfl_down(acc, 4, 64);
        acc += __shfl_down(acc, 2, 64);
        acc += __shfl_down(acc, 1, 64);
        if (sub == 0 && act) {
            float li = logf(acc * h * (1.0f / 3.0f)) + ln2overB;
            part += (li < 0.f) ? li : 0.f;       // betainc <= 1
        }
    }
    for (int off = 32; off > 0; off >>= 1) part += __shfl_down(part, off, 64);
    if ((tid & 63) == 0) wsum[tid >> 6] = part;
    __syncthreads();
    if (tid == 0) {
        float t = 0.f;
        for (int w = 0; w < 8; ++w) t += wsum[w];
        atomAddF(out, -t);
    }
}

// ---------------- launch: 3 graph nodes, 0 memsets ----------------
extern "C" void kernel_launch(void* const* d_in, const int* in_sizes, int n_in,
                              void* d_out, int out_size, void* d_ws, size_t ws_size,
                              hipStream_t stream) {
    const float* hidden = (const float*)d_in[0];
    const int* bids = (const int*)d_in[1];
    const int* dptr = (const int*)d_in[2];
    float* out = (float*)d_out;

    char* ws = (char*)d_ws;
    float* psum  = (float*)(ws);
    float* psq   = (float*)(ws + (16u << 20));
    int*   pcnt  = (int*)  (ws + (32u << 20));
    float* p2sum = (float*)(ws + (32u << 20) + 32768);
    float* p2sq  = (float*)(ws + (32u << 20) + 32768 + 524288);
    int*   cnt2  = (int*)  (ws + (32u << 20) + 32768 + 2 * 524288);

    k_stream<<<NCHUNK * 2, 256, 0, stream>>>(hidden, bids, psum, psq, pcnt);
    k_reduce<<<NUM_C * 2 * GRP, 256, 0, stream>>>(psum, psq, pcnt, p2sum, p2sq, cnt2, out);
    k_pairs <<<NUM_C * (NUM_C - 1) / 2, 512, 0, stream>>>(p2sum, p2sq, cnt2, dptr, out);
}

// Round 11
// 224.444 us; speedup vs baseline: 1.0762x; 1.0143x over previous
//
#include <hip/hip_runtime.h>
#include <math.h>

#define NUM_C 16
#define DIMS 512
#define RPC 256              // rows per chunk in k_stream
#define NCHUNK 256           // 65536 / RPC
#define GRP 16               // reducer groups per (class, half)
#define CPG (NCHUNK / GRP)   // chunks per reducer group = 16

__device__ inline void atomAddF(float* p, float v) { unsafeAtomicAdd(p, v); }

// ws layout:
//   psum (float2) @ 0        : 512 blk * 16 c * 256 d * 8 B = 16 MB
//   pcnt          @ 16 MB    : 256 chunks * 16 ints = 16 KB
//   p2   (float2) @ 16M+16K  : 16 c * 2 g * 16 grp * 256 d * 8 B = 1 MB
//   cnt2          @ +1 MB    : 16*16 ints
// Everything fully written before read -> no memset nodes.

// ---------------- K1: streaming per-chunk per-class {sum,sq} ----------------
// Block = (g = dim-half, chunk of 256 rows); hidden read sequentially.
// Thread t owns LDS slot (c, t) exclusively -> plain float2 RMW: ONE
// ds_read_b64 + ONE ds_write_b64 per element (sum+sq fused), no atomics,
// no __syncthreads. 8-row prefetch. Coalesced float2 partial flush.
__global__ __launch_bounds__(256) void k_stream(const float* __restrict__ hidden,
                                                const int* __restrict__ bids,
                                                float2* __restrict__ psum,
                                                int* __restrict__ pcnt) {
    __shared__ float2 acc[NUM_C * 256];   // 32 KB
    const int tid = threadIdx.x;
    const int g = blockIdx.x & 1;
    const int chunk = blockIdx.x >> 1;

    #pragma unroll
    for (int c = 0; c < NUM_C; ++c) acc[c * 256 + tid] = make_float2(0.f, 0.f);

    const int rowbase = chunk * RPC;
    const float* hp = hidden + (size_t)rowbase * DIMS + g * 256 + tid;
    const int* bp = bids + rowbase;

    int mycnt = 0;   // lanes 0..15: rows in this chunk with class == tid

    float va[8]; int ca[8];
    #pragma unroll
    for (int u = 0; u < 8; ++u) { va[u] = hp[(size_t)u * DIMS]; ca[u] = bp[u]; }

    for (int it = 0; it < RPC / 8 - 1; ++it) {
        float vb[8]; int cb[8];
        const float* hp2 = hp + (size_t)(it + 1) * 8 * DIMS;
        const int* bp2 = bp + (it + 1) * 8;
        #pragma unroll
        for (int u = 0; u < 8; ++u) { vb[u] = hp2[(size_t)u * DIMS]; cb[u] = bp2[u]; }
        #pragma unroll
        for (int u = 0; u < 8; ++u) {
            const int idx = ca[u] * 256 + tid;
            float2 a = acc[idx];
            a.x += va[u];
            a.y += va[u] * va[u];
            acc[idx] = a;
            mycnt += (ca[u] == tid) ? 1 : 0;
        }
        #pragma unroll
        for (int u = 0; u < 8; ++u) { va[u] = vb[u]; ca[u] = cb[u]; }
    }
    #pragma unroll
    for (int u = 0; u < 8; ++u) {
        const int idx = ca[u] * 256 + tid;
        float2 a = acc[idx];
        a.x += va[u];
        a.y += va[u] * va[u];
        acc[idx] = a;
        mycnt += (ca[u] == tid) ? 1 : 0;
    }

    // flush own column -> coalesced float2 partial stores (2 KB per class)
    float2* ps = psum + (size_t)blockIdx.x * NUM_C * 256 + tid;
    #pragma unroll
    for (int c = 0; c < NUM_C; ++c) ps[c * 256] = acc[c * 256 + tid];
    if (g == 0 && tid < NUM_C) pcnt[chunk * NUM_C + tid] = mycnt;
}

// ---------------- K2: tree-reduce partials (no atomics) ----------------
// 512 blocks = (c, g, grp); each sums 16 chunks' float2 segments (coalesced),
// writes one 2 KB segment of p2. g==0/tid==0 reduces counts. Block 0 zeroes
// out (stream-ordered before k_pairs).
__global__ __launch_bounds__(256) void k_reduce(const float2* __restrict__ psum,
                                                const int* __restrict__ pcnt,
                                                float2* __restrict__ p2,
                                                int* __restrict__ cnt2,
                                                float* __restrict__ out) {
    const int tid = threadIdx.x;
    const int bid = blockIdx.x;
    const int c = bid >> 5;
    const int g = (bid >> 4) & 1;
    const int grp = bid & 15;
    if (bid == 0 && tid == 0) out[0] = 0.f;

    float s = 0.f, q = 0.f;
    #pragma unroll 4
    for (int k = 0; k < CPG; ++k) {
        const int chunk = grp * CPG + k;
        const float2 v = psum[((size_t)(chunk * 2 + g) * NUM_C + c) * 256 + tid];
        s += v.x; q += v.y;
    }
    p2[((c * 2 + g) * GRP + grp) * 256 + tid] = make_float2(s, q);

    if (g == 0 && tid == 0) {
        int cc = 0;
        #pragma unroll
        for (int k = 0; k < CPG; ++k) cc += pcnt[(grp * CPG + k) * NUM_C + c];
        cnt2[c * GRP + grp] = cc;
    }
}

// ---------------- K3: pairs — reduce p2 inline, sort, Simpson betainc -------
// I_x(1/2,b) = (2/B(1/2,b)) * Int_0^sqrt(x) (1-u^2)^(b-1) du
// Composite Simpson (256 intervals), f32, 8 lanes per x-value.
// Monotone in x -> top-d of betainc == betainc of top-d x (sort x only).
__global__ __launch_bounds__(512) void k_pairs(const float2* __restrict__ p2,
                                               const int* __restrict__ cnt2,
                                               const int* __restrict__ dptr,
                                               float* __restrict__ out) {
    __shared__ float xs[DIMS];
    __shared__ float wsum[8];
    const int tid = threadIdx.x;

    int p = blockIdx.x, i = 0, rem = p;
    while (rem >= NUM_C - 1 - i) { rem -= NUM_C - 1 - i; ++i; }
    const int j = i + 1 + rem;

    int cnti = 0, cntj = 0;
    #pragma unroll
    for (int gq = 0; gq < GRP; ++gq) { cnti += cnt2[i * GRP + gq]; cntj += cnt2[j * GRP + gq]; }
    const float ni = (float)cnti, nj = (float)cntj;
    const float pc = ni + nj;

    {
        const int g = tid >> 8, dl = tid & 255;
        float si = 0.f, qi = 0.f, sj = 0.f, qj = 0.f;
        #pragma unroll
        for (int gq = 0; gq < GRP; ++gq) {
            const float2 a = p2[((i * 2 + g) * GRP + gq) * 256 + dl];
            const float2 b = p2[((j * 2 + g) * GRP + gq) * 256 + dl];
            si += a.x; qi += a.y;
            sj += b.x; qj += b.y;
        }
        const float mi = si / ni, mj = sj / nj;
        float wi = qi - si * mi;  wi = wi > 0.f ? wi : 0.f;
        float wj = qj - sj * mj;  wj = wj > 0.f ? wj : 0.f;
        const float hd = (mi - mj) * 0.5f;
        const float between = hd * hd * pc;
        const float within = wi + wj;
        float x = between / (between + within);
        if (!(x >= 1e-37f)) x = 1e-37f;          // also catches NaN
        const float XM = 1.0f - 1e-5f;
        if (x > XM) x = XM;
        xs[tid] = x;
    }

    // bitonic sort descending (f32)
    for (int kk = 2; kk <= DIMS; kk <<= 1) {
        for (int jj = kk >> 1; jj > 0; jj >>= 1) {
            __syncthreads();
            const int ixj = tid ^ jj;
            if (ixj > tid) {
                const float va = xs[tid], vb = xs[ixj];
                const bool sw = ((tid & kk) == 0) ? (va < vb) : (va > vb);
                if (sw) { xs[tid] = vb; xs[ixj] = va; }
            }
        }
    }
    __syncthreads();

    const int d = *dptr;
    float d2 = pc - 2.0f;
    if (d2 == 0.0f) d2 = 1e-5f;
    const float b = d2 * 0.5f;
    const float bm1 = b - 1.0f;
    const float invb = 1.0f / b;
    // ln(2/B) = ln2 - [0.5*(ln pi - ln b) + log1p(1/(8b) + 1/(128 b^2))]
    const float ln2overB = 0.69314718f
        - (0.5f * (1.14472989f - logf(b)) + log1pf(invb * (0.125f + 0.0078125f * invb)));

    const int sub = tid & 7;
    const int rounds = (d + 63) >> 6;            // q-groups of 64 per pass
    float part = 0.f;
    for (int r = 0; r < rounds; ++r) {
        const int q = (tid >> 3) + (r << 6);
        const bool act = (q < d);
        const float x = xs[act ? q : 0];
        const float rt = sqrtf(x);
        const float h = rt * (1.0f / 256.0f);
        float acc = 0.f;
        for (int k = sub; k <= 256; k += 8) {
            const float sv = (float)k * h;
            const float w = (k == 0 || k == 256) ? 1.f : ((k & 1) ? 4.f : 2.f);
            acc += w * __expf(bm1 * log1pf(-sv * sv));
        }
        acc += __shfl_down(acc, 4, 64);
        acc += __shfl_down(acc, 2, 64);
        acc += __shfl_down(acc, 1, 64);
        if (sub == 0 && act) {
            float li = logf(acc * h * (1.0f / 3.0f)) + ln2overB;
            part += (li < 0.f) ? li : 0.f;       // betainc <= 1
        }
    }
    for (int off = 32; off > 0; off >>= 1) part += __shfl_down(part, off, 64);
    if ((tid & 63) == 0) wsum[tid >> 6] = part;
    __syncthreads();
    if (tid == 0) {
        float t = 0.f;
        for (int w = 0; w < 8; ++w) t += wsum[w];
        atomAddF(out, -t);
    }
}

// ---------------- launch: 3 graph nodes, 0 memsets ----------------
extern "C" void kernel_launch(void* const* d_in, const int* in_sizes, int n_in,
                              void* d_out, int out_size, void* d_ws, size_t ws_size,
                              hipStream_t stream) {
    const float* hidden = (const float*)d_in[0];
    const int* bids = (const int*)d_in[1];
    const int* dptr = (const int*)d_in[2];
    float* out = (float*)d_out;

    char* ws = (char*)d_ws;
    float2* psum = (float2*)(ws);
    int*    pcnt = (int*)   (ws + (16u << 20));
    float2* p2   = (float2*)(ws + (16u << 20) + 16384);
    int*    cnt2 = (int*)   (ws + (16u << 20) + 16384 + (1u << 20));

    k_stream<<<NCHUNK * 2, 256, 0, stream>>>(hidden, bids, psum, pcnt);
    k_reduce<<<NUM_C * 2 * GRP, 256, 0, stream>>>(psum, pcnt, p2, cnt2, out);
    k_pairs <<<NUM_C * (NUM_C - 1) / 2, 512, 0, stream>>>(p2, cnt2, dptr, out);
}